// Round 8
// baseline (216.683 us; speedup 1.0000x reference)
//
#include <hip/hip_runtime.h>

// Capsule dynamic routing via MFMA, fused, u_hat never materialized.
//   x: [B=64, In=2048, K=16] fp32;  W: [N=32, In=2048, D=32, K=16] fp32
//   out v: [B=64, N=32, D=32] fp32
// Identities: b_t = u_hat . Vsum (logits linear in agreements); c_1 = 1/32.
// Per (n,i): u[d,b] = W[n,i] (32x16) @ x^T (16x64) via 2 b-tiles of
// mfma_f32_32x32x16_bf16.
// Round-8 structure: kWc = pure streaming W->bf16 convert (201 MB, ~7TB/s
// pattern); ALL three iterations run Wb-based kS (iter 1 via uniform-c flag).
// kA (logit pass) uses single-MFMA u (x-hi only; softmax-damped error).
// kS (s accumulation) keeps x hi+lo split. ct/spart bf16.
// NOTE (round-3): tiny-grid reduction kernels are latency disasters.
// NOTE (round-5): fusing two W passes across a block barrier refetches W.
// NOTE (round-6/7): these kernels are latency-bound, not BW/MFMA-bound;
// wave count and short dep chains are what matters.

#define INP 2048
#define BB 64
#define KK 16
#define NN 32
#define DD 32
#define ICH 16
#define NCHUNK (INP / ICH) // 128

typedef __attribute__((ext_vector_type(8))) short short8;
typedef __attribute__((ext_vector_type(16))) float f32x16;

__device__ __forceinline__ short bf_trunc(float f) {
  return (short)(__builtin_bit_cast(unsigned, f) >> 16);
}
__device__ __forceinline__ unsigned short bf_round(float f) {
  unsigned u = __builtin_bit_cast(unsigned, f);
  return (unsigned short)((u + 0x8000u) >> 16);
}
__device__ __forceinline__ float bf2f(unsigned short u) {
  return __builtin_bit_cast(float, (unsigned)u << 16);
}

__device__ __forceinline__ void split8(float4 w0, float4 w1, short8& h, short8& l) {
  float f[8] = {w0.x, w0.y, w0.z, w0.w, w1.x, w1.y, w1.z, w1.w};
#pragma unroll
  for (int j = 0; j < 8; ++j) {
    unsigned u = __builtin_bit_cast(unsigned, f[j]);
    h[j] = (short)(u >> 16);
    float hf = __builtin_bit_cast(float, u & 0xFFFF0000u);
    l[j] = bf_trunc(f[j] - hf);
  }
}

// round-to-nearest bf16 of 8 fp32
__device__ __forceinline__ short8 round8(float4 w0, float4 w1) {
  float f[8] = {w0.x, w0.y, w0.z, w0.w, w1.x, w1.y, w1.z, w1.w};
  short8 r;
#pragma unroll
  for (int j = 0; j < 8; ++j) r[j] = (short)bf_round(f[j]);
  return r;
}

// ------------------------------------------------------------------ kWc
// pure streaming convert: W fp32 -> Wb bf16 (same layout, elementwise).
__global__ __launch_bounds__(256) void kWc(const float* __restrict__ W,
                                           short* __restrict__ Wb) {
  const size_t stride = (size_t)gridDim.x * 256;
  const size_t nch = (size_t)NN * INP * DD * KK / 8; // 4,194,304 float8 chunks
  const float4* W4 = (const float4*)W;
  short8* Wb8 = (short8*)Wb;
  for (size_t t = (size_t)blockIdx.x * 256 + threadIdx.x; t < nch; t += stride)
    Wb8[t] = round8(W4[2 * t], W4[2 * t + 1]);
}

// ------------------------------------------------------------------ kT
// transpose x [B][In][K] fp32 -> xt_hi/xt_lo [In][B][K] bf16
__global__ __launch_bounds__(256) void kT(const float* __restrict__ x,
                                          short* __restrict__ xh,
                                          short* __restrict__ xl) {
  const int t = blockIdx.x * 256 + threadIdx.x; // In*B = 131072
  const int i = t >> 6, b = t & 63;
  const float4* xs = (const float4*)(x + ((size_t)b * INP + i) * KK);
  short8* dh = (short8*)(xh + ((size_t)i * BB + b) * KK);
  short8* dl = (short8*)(xl + ((size_t)i * BB + b) * KK);
#pragma unroll
  for (int h = 0; h < 2; ++h) {
    short8 hh, ll;
    split8(xs[h * 2], xs[h * 2 + 1], hh, ll);
    dh[h] = hh;
    dl[h] = ll;
  }
}

// ------------------------------------------------------------------ kA
// wave = (n, i-chunk). a[b,n,i] = sum_d u[d,b]*vsum[b,n,d] -> ct bf16 (raw).
// single-MFMA u (x hi only): logit error is softmax-damped + i-averaged.
__global__ __launch_bounds__(256) void kA(const short* __restrict__ Wb,
                                          const short* __restrict__ xh,
                                          const float* __restrict__ vsum,
                                          unsigned short* __restrict__ ct) {
  const int wv = threadIdx.x >> 6;
  const int lane = threadIdx.x & 63;
  const int bl = lane & 31;
  const int hi = lane >> 5;
  const int w = blockIdx.x * 4 + wv;
  const int n = w >> 7;
  const int ch = w & (NCHUNK - 1);

  float vr0[16], vr1[16];
#pragma unroll
  for (int r = 0; r < 16; ++r) {
    const int d = (r & 3) + 8 * (r >> 2) + 4 * hi;
    vr0[r] = vsum[((size_t)n * DD + d) * BB + bl];
    vr1[r] = vsum[((size_t)n * DD + d) * BB + bl + 32];
  }

  const short* Wp = Wb + (((size_t)n * INP + (size_t)ch * ICH) * DD + bl) * KK + hi * 8;
  const short* xhp = xh + (size_t)ch * ICH * BB * KK + hi * 8;

#pragma unroll 2
  for (int ii = 0; ii < ICH; ++ii) {
    const short8 whi = *(const short8*)(Wp + (size_t)ii * (DD * KK));
    const short8 x0h = *(const short8*)(xhp + ii * (BB * KK) + bl * KK);
    const short8 x1h = *(const short8*)(xhp + ii * (BB * KK) + (bl + 32) * KK);

    f32x16 u0 = {};
    u0 = __builtin_amdgcn_mfma_f32_32x32x16_bf16(whi, x0h, u0, 0, 0, 0);
    f32x16 u1 = {};
    u1 = __builtin_amdgcn_mfma_f32_32x32x16_bf16(whi, x1h, u1, 0, 0, 0);

    float p0 = 0.f, p1 = 0.f;
#pragma unroll
    for (int r = 0; r < 16; ++r) {
      p0 += u0[r] * vr0[r];
      p1 += u1[r] * vr1[r];
    }
    p0 += __shfl_xor(p0, 32, 64);
    p1 += __shfl_xor(p1, 32, 64);
    const int i = ch * ICH + ii;
    ct[((size_t)i * NN + n) * BB + lane] = bf_round((lane < 32) ? p0 : p1);
  }
}

// ------------------------------------------------------------------ kSM
// in-place softmax over n for each (i, b); wave per i, lane = b. bf16 ct.
__global__ __launch_bounds__(256) void kSM(unsigned short* __restrict__ ct) {
  const int wv = threadIdx.x >> 6;
  const int lane = threadIdx.x & 63;
  const int i = blockIdx.x * 4 + wv;
  unsigned short* p = ct + (size_t)i * NN * BB + lane;
  float a[NN];
  float m = -1e30f;
#pragma unroll
  for (int n = 0; n < NN; ++n) {
    a[n] = bf2f(p[n * BB]);
    m = fmaxf(m, a[n]);
  }
  float s = 0.f;
#pragma unroll
  for (int n = 0; n < NN; ++n) {
    a[n] = __expf(a[n] - m);
    s += a[n];
  }
  const float inv = 1.f / s;
#pragma unroll
  for (int n = 0; n < NN; ++n) p[n * BB] = bf_round(a[n] * inv);
}

// ------------------------------------------------------------------ kS
// all iterations: wave = (n, i-chunk). s_acc += c * u; bf16 spart.
// uniform_c=1 (iter 1): c = 1/32 (softmax of zero logits).
__global__ __launch_bounds__(256) void kS(const short* __restrict__ Wb,
                                          const short* __restrict__ xh,
                                          const short* __restrict__ xl,
                                          const unsigned short* __restrict__ ct,
                                          unsigned short* __restrict__ spart,
                                          int uniform_c) {
  const int wv = threadIdx.x >> 6;
  const int lane = threadIdx.x & 63;
  const int bl = lane & 31;
  const int hi = lane >> 5;
  const int w = blockIdx.x * 4 + wv;
  const int n = w >> 7;
  const int ch = w & (NCHUNK - 1);

  f32x16 s0 = {};
  f32x16 s1 = {};

  const short* Wp = Wb + (((size_t)n * INP + (size_t)ch * ICH) * DD + bl) * KK + hi * 8;
  const short* xhp = xh + (size_t)ch * ICH * BB * KK + hi * 8;
  const short* xlp = xl + (size_t)ch * ICH * BB * KK + hi * 8;

#pragma unroll 2
  for (int ii = 0; ii < ICH; ++ii) {
    const short8 whi = *(const short8*)(Wp + (size_t)ii * (DD * KK));
    const short8 x0h = *(const short8*)(xhp + ii * (BB * KK) + bl * KK);
    const short8 x0l = *(const short8*)(xlp + ii * (BB * KK) + bl * KK);
    const short8 x1h = *(const short8*)(xhp + ii * (BB * KK) + (bl + 32) * KK);
    const short8 x1l = *(const short8*)(xlp + ii * (BB * KK) + (bl + 32) * KK);

    f32x16 u0 = {};
    u0 = __builtin_amdgcn_mfma_f32_32x32x16_bf16(whi, x0h, u0, 0, 0, 0);
    u0 = __builtin_amdgcn_mfma_f32_32x32x16_bf16(whi, x0l, u0, 0, 0, 0);
    f32x16 u1 = {};
    u1 = __builtin_amdgcn_mfma_f32_32x32x16_bf16(whi, x1h, u1, 0, 0, 0);
    u1 = __builtin_amdgcn_mfma_f32_32x32x16_bf16(whi, x1l, u1, 0, 0, 0);

    float c0, c1;
    if (uniform_c) {
      c0 = 0.03125f;
      c1 = 0.03125f;
    } else {
      const int i = ch * ICH + ii;
      c0 = bf2f(ct[((size_t)i * NN + n) * BB + bl]);
      c1 = bf2f(ct[((size_t)i * NN + n) * BB + bl + 32]);
    }
#pragma unroll
    for (int r = 0; r < 16; ++r) {
      s0[r] += c0 * u0[r];
      s1[r] += c1 * u1[r];
    }
  }

  const size_t off = ((size_t)ch * NN + n) * (DD * BB);
#pragma unroll
  for (int r = 0; r < 16; ++r) {
    const int d = (r & 3) + 8 * (r >> 2) + 4 * hi;
    spart[off + d * BB + bl] = bf_round(s0[r]);
    spart[off + d * BB + bl + 32] = bf_round(s1[r]);
  }
}

// ------------------------------------------------------------------ kR1h
// bf16 spart [128][N][D][B] -> st fp32; uint loads (2 elems/thread).
__global__ void kR1h(const unsigned* __restrict__ spart, float2* __restrict__ st) {
  const int t = blockIdx.x * 128 + threadIdx.x; // 32768 uint cells
  float s0 = 0.f, s1 = 0.f;
  for (int ch = 0; ch < NCHUNK; ++ch) {
    const unsigned u = spart[(size_t)ch * (NN * DD * BB / 2) + t];
    s0 += bf2f((unsigned short)(u & 0xFFFFu));
    s1 += bf2f((unsigned short)(u >> 16));
  }
  st[t] = make_float2(s0, s1);
}

// ------------------------------------------------------------------ kR2
// squash per (b,n); vsum = (first ? v : vsum + v); write out on last.
__global__ void kR2(const float* __restrict__ st, float* __restrict__ vsum,
                    float* __restrict__ out, int first, int last) {
  const int t = blockIdx.x * 64 + threadIdx.x; // B*N = 2048
  const int b = t & 63;
  const int n = t >> 6;
  float sd[DD];
  float s2 = 0.f;
#pragma unroll
  for (int d = 0; d < DD; ++d) {
    sd[d] = st[(n * DD + d) * BB + b];
    s2 += sd[d] * sd[d];
  }
  const float scale = s2 / (1.f + s2) / sqrtf(s2 + 1e-7f);
#pragma unroll
  for (int d = 0; d < DD; ++d) {
    const float v = scale * sd[d];
    const size_t idx = (size_t)(n * DD + d) * BB + b;
    vsum[idx] = first ? v : (vsum[idx] + v);
    if (last) out[((size_t)b * NN + n) * DD + d] = v;
  }
}

extern "C" void kernel_launch(void* const* d_in, const int* in_sizes, int n_in,
                              void* d_out, int out_size, void* d_ws,
                              size_t ws_size, hipStream_t stream) {
  const float* x = (const float*)d_in[0]; // [64,2048,16]
  const float* W = (const float*)d_in[1]; // [32,2048,32,16]
  float* out = (float*)d_out;             // [64,32,32]

  short* xh = (short*)d_ws;                            // [In][B][K] bf16 4.2 MB
  short* xl = xh + (size_t)INP * BB * KK;              // 4.2 MB
  short* Wbuf = xl + (size_t)INP * BB * KK;            // [N][In][D][K] bf16 67 MB
  unsigned short* ct = (unsigned short*)(Wbuf + (size_t)NN * INP * DD * KK); // 8.4 MB
  unsigned short* sparth = ct + (size_t)INP * NN * BB; // [128][N][D][B] bf16 16.8 MB
  float* st = (float*)(sparth + (size_t)NCHUNK * NN * DD * BB); // 256 KB
  float* vsum = st + (size_t)NN * DD * BB;                       // 256 KB

  const int gW = (NN * NCHUNK) / 4;          // 1024 blocks, 4 waves each
  const int gT = (INP * BB) / 256;           // 512
  const int gSM = INP / 4;                   // 512
  const int gR1h = (NN * DD * BB / 2) / 128; // 256
  const int gR2 = (BB * NN) / 64;            // 32

  kWc<<<2048, 256, 0, stream>>>(W, Wbuf);
  kT<<<gT, 256, 0, stream>>>(x, xh, xl);

  // iteration 1: c uniform (softmax of zero logits); vsum = v (first)
  kS<<<gW, 256, 0, stream>>>(Wbuf, xh, xl, (const unsigned short*)nullptr, sparth, 1);
  kR1h<<<gR1h, 128, 0, stream>>>((const unsigned*)sparth, (float2*)st);
  kR2<<<gR2, 64, 0, stream>>>(st, vsum, out, 1, 0);
  // iterations 2..3
  for (int it = 1; it < 3; ++it) {
    kA<<<gW, 256, 0, stream>>>(Wbuf, xh, vsum, ct);
    kSM<<<gSM, 256, 0, stream>>>(ct);
    kS<<<gW, 256, 0, stream>>>(Wbuf, xh, xl, ct, sparth, 0);
    kR1h<<<gR1h, 128, 0, stream>>>((const unsigned*)sparth, (float2*)st);
    kR2<<<gR2, 64, 0, stream>>>(st, vsum, out, 0, it == 2);
  }
}